// Round 10
// baseline (209.727 us; speedup 1.0000x reference)
//
#include <hip/hip_runtime.h>
#include <hip/hip_bf16.h>
#include <math.h>

// Problem constants
#define HID   64
#define VOCABN 64
#define INNER 24
#define SEQN  32
#define CAPN  8
#define NPOS  17
#define BATCHN 8192

typedef float f32x4 __attribute__((ext_vector_type(4)));

// Per-step Adam prefactor (double-precision offline):
//   cmsbr[t] = LR * sqrt(1 - B2^(t+1)) / (1 - B1^(t+1)),  t = 0..7
static __device__ const float CMSBR[8] = {
  0.01581139f, 0.01176584f, 0.01010053f, 0.00918844f,
  0.00862495f, 0.00825540f, 0.00800653f, 0.00783856f
};

// ---------- cross-lane all-reduce, xor-butterfly (bit-exact lineage r4-r9) ----------
__device__ __forceinline__ float allred64(float x) {
  int y;
  y = __builtin_amdgcn_update_dpp(__float_as_int(x), __float_as_int(x),
                                  0xB1, 0xF, 0xF, false);   // quad_perm xor1
  x += __int_as_float(y);
  y = __builtin_amdgcn_update_dpp(__float_as_int(x), __float_as_int(x),
                                  0x4E, 0xF, 0xF, false);   // quad_perm xor2
  x += __int_as_float(y);
  x += __int_as_float(__builtin_amdgcn_ds_swizzle(__float_as_int(x), 0x101F)); // xor4
  x += __int_as_float(__builtin_amdgcn_ds_swizzle(__float_as_int(x), 0x201F)); // xor8
  x += __int_as_float(__builtin_amdgcn_ds_swizzle(__float_as_int(x), 0x401F)); // xor16
  x += __shfl_xor(x, 32);
  return x;
}

// ---------- Kernel 1: per-token encoder table (verbatim round 6, passing) ----------
__global__ __launch_bounds__(128) void build_table(
    const float* __restrict__ embed,    // [64][64]
    const float* __restrict__ ff_w1,    // [64][128]
    const float* __restrict__ ff_b1,    // [128]
    const float* __restrict__ ff_w2,    // [128][64]
    const float* __restrict__ ff_b2,    // [64]
    const float* __restrict__ ln_g,     // [64]
    const float* __restrict__ ln_b,     // [64]
    float* __restrict__ etab)           // [64][64]
{
  __shared__ float h[64];
  __shared__ float A1[128];
  __shared__ float xs[64];
  const int r = blockIdx.x;
  const int t = threadIdx.x;

  if (t < 64) h[t] = embed[r * 64 + t];
  __syncthreads();

  {
    float acc = ff_b1[t];
    #pragma unroll 8
    for (int k = 0; k < 64; ++k)
      acc = fmaf(h[k], ff_w1[k * 128 + t], acc);
    A1[t] = fmaxf(acc, 0.f);
  }
  __syncthreads();

  if (t < 64) {
    float acc = ff_b2[t];
    #pragma unroll 8
    for (int k = 0; k < 128; ++k)
      acc = fmaf(A1[k], ff_w2[k * 64 + t], acc);
    xs[t] = acc + h[t];
  }
  __syncthreads();

  if (t < 64) {
    float s1 = 0.f;
    if (t < 4)
      for (int j = 0; j < 16; ++j) s1 += xs[t + 4 * j];
    s1 += __shfl_xor(s1, 1);
    s1 += __shfl_xor(s1, 2);
    s1 = __shfl(s1, 0);
    float mu = s1 * 0.015625f;

    float s2 = 0.f;
    if (t < 4)
      for (int j = 0; j < 16; ++j) {
        float d = xs[t + 4 * j] - mu;
        s2 = fmaf(d, d, s2);
      }
    s2 += __shfl_xor(s2, 1);
    s2 += __shfl_xor(s2, 2);
    s2 = __shfl(s2, 0);
    float var = s2 * 0.015625f;
    float rs  = rsqrtf(var + 1e-5f);

    etab[r * 64 + t] = fmaf((xs[t] - mu) * rs, ln_g[t], ln_b[t]);
  }
}

// ---------- Kernel 2: 2-wave-per-sample 8-step Adam ----------
// Adam math identical to round 9 (passing, absmax 0.0352).
__device__ __forceinline__ void adam_upd(float& p, float& m, float& v,
                                         float g1, float g2, float cmsbr) {
  m = fmaf(0.9f, m, g1);
  v = fmaf(0.999f, v, g2);
  p = fmaf(-(m * cmsbr), __builtin_amdgcn_rsqf(fmaxf(v, 1e-30f)), p);
}

// NOTE: no min-waves hint. r9's (128,3) made the allocator target the 8-wave
// tier (64 arch VGPRs) and push ~25 live Adam-state floats into AGPRs —
// paying v_accvgpr_read/write on every m/v touch (~100 extra VALU/step).
// Unconstrained, the allocator can keep all ~90 live values in real VGPRs
// (4-wave occupancy tier, zero cross-file moves).
__global__ __launch_bounds__(128) void adapt_kernel(
    const int* __restrict__ seqs,       // [BATCH][32]
    const float* __restrict__ etab,     // [64][64]
    const float* __restrict__ mlp_w1,   // [64][24]
    const float* __restrict__ mlp_b1,   // [24]
    const float* __restrict__ mlp_w2,   // [24][64]
    const float* __restrict__ mlp_b2,   // [64]
    const float* __restrict__ out_w,    // [64][64]
    const float* __restrict__ out_b,    // [64]
    float* __restrict__ out)            // [BATCH][64]
{
  __shared__ float ybuf[2][2][64];     // [step parity][wave][col]
  __shared__ float hqv[64];
  const int t    = threadIdx.x;        // 0..127
  const int lane = t & 63;
  const int w    = t >> 6;             // 0 or 1
  const int s    = blockIdx.x;
  const int i0   = 12 * w;

  int tok = (lane < NPOS) ? seqs[s * SEQN + 14 + lane] : 0;

  // state: lane j owns w1[j][i0..i0+12), w2[i0..i0+12)[j];
  // lanes<12 own b1[i0+lane]; wave0 owns b2[lane].
  float w1r[12], m1[12], v1[12], w2c[12], m2[12], v2[12];
  #pragma unroll
  for (int i = 0; i < 12; ++i) {
    w1r[i] = mlp_w1[lane * 24 + i0 + i];
    w2c[i] = mlp_w2[(i0 + i) * 64 + lane];
    m1[i] = 0.f; v1[i] = 0.f; m2[i] = 0.f; v2[i] = 0.f;
  }
  float b1o = (lane < 12) ? mlp_b1[i0 + lane] : 0.f;
  float b2o = (w == 0) ? mlp_b2[lane] : 0.f;
  float mb1 = 0.f, vb1 = 0.f, mb2 = 0.f, vb2 = 0.f;

  // first k,v rows (direct from L2-resident etab)
  int tk = __shfl(tok, 0), tv = __shfl(tok, 1);
  float kj = etab[tk * 64 + lane];
  float vj = etab[tv * 64 + lane];

  #pragma unroll 1
  for (int st = 0; st < 8; ++st) {
    const float cmsbr = CMSBR[st];

    // forward: z_i (i in wave's half) = allred(k_j * w1[j][i]) + b1
    float zp[12];
    #pragma unroll
    for (int i = 0; i < 12; ++i) zp[i] = kj * w1r[i];
    #pragma unroll
    for (int i = 0; i < 12; ++i) zp[i] += (lane == i) ? b1o : 0.f;
    #pragma unroll
    for (int i = 0; i < 12; ++i) zp[i] = allred64(zp[i]);

    float a[12];
    #pragma unroll
    for (int i = 0; i < 12; ++i) a[i] = fmaxf(zp[i], 0.f);

    // y partial over this wave's 12 inner dims; b2 only in wave0's partial
    float yp = (w == 0) ? b2o : 0.f;
    #pragma unroll
    for (int i = 0; i < 12; ++i) yp = fmaf(a[i], w2c[i], yp);
    ybuf[st & 1][w][lane] = yp;
    __syncthreads();
    float y = ybuf[st & 1][0][lane] + ybuf[st & 1][1][lane];
    float dy = (y - vj) * 0.03125f;   // 2/64

    // prefetch next step's k,v (st=7 harmlessly loads q row twice)
    int p1 = 2 * st + 2; p1 = p1 < 16 ? p1 : 16;
    int p2 = 2 * st + 3; p2 = p2 < 16 ? p2 : 16;
    int tk2 = __shfl(tok, p1), tv2 = __shfl(tok, p2);
    float kn = etab[tk2 * 64 + lane];
    float vn = etab[tv2 * 64 + lane];

    // backward: dz_i = (z_i>0) * allred(w2[i][c]*dy_c)
    float dz[12];
    #pragma unroll
    for (int i = 0; i < 12; ++i) dz[i] = w2c[i] * dy;
    #pragma unroll
    for (int i = 0; i < 12; ++i) dz[i] = allred64(dz[i]);
    #pragma unroll
    for (int i = 0; i < 12; ++i) dz[i] = (a[i] > 0.f) ? dz[i] : 0.f;

    // Adam step st+1; gradient prefactors folded per step
    float kj01 = 0.1f   * kj;
    float kjsq = 0.001f * kj * kj;
    float dy01 = 0.1f   * dy;
    float dysq = 0.001f * dy * dy;
    #pragma unroll
    for (int i = 0; i < 12; ++i)
      adam_upd(w1r[i], m1[i], v1[i], kj01 * dz[i], kjsq * (dz[i] * dz[i]), cmsbr);
    #pragma unroll
    for (int i = 0; i < 12; ++i)
      adam_upd(w2c[i], m2[i], v2[i], dy01 * a[i], dysq * (a[i] * a[i]), cmsbr);
    adam_upd(b2o, mb2, vb2, dy01, dysq, cmsbr);      // wave1's copy never read
    float gb1 = 0.f;
    #pragma unroll
    for (int i = 0; i < 12; ++i) gb1 = (lane == i) ? dz[i] : gb1;
    adam_upd(b1o, mb1, vb1, 0.1f * gb1, 0.001f * (gb1 * gb1), cmsbr);

    kj = kn; vj = vn;
  }

  // final forward with q (kj holds q row after last prefetch)
  float zq[12];
  #pragma unroll
  for (int i = 0; i < 12; ++i) zq[i] = kj * w1r[i];
  #pragma unroll
  for (int i = 0; i < 12; ++i) zq[i] += (lane == i) ? b1o : 0.f;
  #pragma unroll
  for (int i = 0; i < 12; ++i) zq[i] = allred64(zq[i]);
  float hp = (w == 0) ? b2o : 0.f;
  #pragma unroll
  for (int i = 0; i < 12; ++i) hp = fmaf(fmaxf(zq[i], 0.f), w2c[i], hp);

  ybuf[0][w][lane] = hp;
  __syncthreads();
  hqv[lane] = ybuf[0][0][lane] + ybuf[0][1][lane];  // both waves, same bits
  __syncthreads();

  // out[s][c] = sum_j hq[j]*out_w[j][c] + out_b[c], split: wave w does
  // j in [32w, 32w+32); combine via LDS. (Output-side reorder only.)
  {
    float acc = (w == 0) ? out_b[lane] : 0.f;
    const f32x4* hv = (const f32x4*)hqv;
    #pragma unroll
    for (int q4 = 0; q4 < 8; ++q4) {
      int j4 = 8 * w + q4;
      f32x4 h4 = hv[j4];
      acc = fmaf(h4.x, out_w[(4 * j4 + 0) * 64 + lane], acc);
      acc = fmaf(h4.y, out_w[(4 * j4 + 1) * 64 + lane], acc);
      acc = fmaf(h4.z, out_w[(4 * j4 + 2) * 64 + lane], acc);
      acc = fmaf(h4.w, out_w[(4 * j4 + 3) * 64 + lane], acc);
    }
    ybuf[1][w][lane] = acc;
    __syncthreads();
    if (w == 0)
      out[(size_t)s * 64 + lane] = ybuf[1][0][lane] + ybuf[1][1][lane];
  }
}

extern "C" void kernel_launch(void* const* d_in, const int* in_sizes, int n_in,
                              void* d_out, int out_size, void* d_ws, size_t ws_size,
                              hipStream_t stream) {
  const int*   seqs   = (const int*)d_in[0];
  const float* embed  = (const float*)d_in[1];
  const float* ff_w1  = (const float*)d_in[2];
  const float* ff_b1  = (const float*)d_in[3];
  const float* ff_w2  = (const float*)d_in[4];
  const float* ff_b2  = (const float*)d_in[5];
  const float* ln_g   = (const float*)d_in[6];
  const float* ln_b   = (const float*)d_in[7];
  const float* mlp_w1 = (const float*)d_in[8];
  const float* mlp_b1 = (const float*)d_in[9];
  const float* mlp_w2 = (const float*)d_in[10];
  const float* mlp_b2 = (const float*)d_in[11];
  const float* out_w  = (const float*)d_in[12];
  const float* out_b  = (const float*)d_in[13];

  float* etab = (float*)d_ws;   // 64*64 f32 = 16 KB

  build_table<<<64, 128, 0, stream>>>(
      embed, ff_w1, ff_b1, ff_w2, ff_b2, ln_g, ln_b, etab);
  adapt_kernel<<<BATCHN, 128, 0, stream>>>(
      seqs, etab, mlp_w1, mlp_b1, mlp_w2, mlp_b2, out_w, out_b,
      (float*)d_out);
}

// Round 11
// 209.351 us; speedup vs baseline: 1.0018x; 1.0018x over previous
//
#include <hip/hip_runtime.h>
#include <hip/hip_bf16.h>
#include <math.h>

// Problem constants
#define HID   64
#define VOCABN 64
#define INNER 24
#define SEQN  32
#define CAPN  8
#define NPOS  17
#define BATCHN 8192

typedef float f32x4 __attribute__((ext_vector_type(4)));

// Per-step Adam prefactor (double-precision offline):
//   cmsbr[t] = LR * sqrt(1 - B2^(t+1)) / (1 - B1^(t+1)),  t = 0..7
static __device__ const float CMSBR[8] = {
  0.01581139f, 0.01176584f, 0.01010053f, 0.00918844f,
  0.00862495f, 0.00825540f, 0.00800653f, 0.00783856f
};

// ---------- cross-lane all-reduce, xor-butterfly (bit-exact lineage r4-r10) ----------
__device__ __forceinline__ float allred64(float x) {
  int y;
  y = __builtin_amdgcn_update_dpp(__float_as_int(x), __float_as_int(x),
                                  0xB1, 0xF, 0xF, false);   // quad_perm xor1
  x += __int_as_float(y);
  y = __builtin_amdgcn_update_dpp(__float_as_int(x), __float_as_int(x),
                                  0x4E, 0xF, 0xF, false);   // quad_perm xor2
  x += __int_as_float(y);
  x += __int_as_float(__builtin_amdgcn_ds_swizzle(__float_as_int(x), 0x101F)); // xor4
  x += __int_as_float(__builtin_amdgcn_ds_swizzle(__float_as_int(x), 0x201F)); // xor8
  x += __int_as_float(__builtin_amdgcn_ds_swizzle(__float_as_int(x), 0x401F)); // xor16
  x += __shfl_xor(x, 32);
  return x;
}

// ---------- Kernel 1: per-token encoder table (verbatim round 6, passing) ----------
__global__ __launch_bounds__(128) void build_table(
    const float* __restrict__ embed,    // [64][64]
    const float* __restrict__ ff_w1,    // [64][128]
    const float* __restrict__ ff_b1,    // [128]
    const float* __restrict__ ff_w2,    // [128][64]
    const float* __restrict__ ff_b2,    // [64]
    const float* __restrict__ ln_g,     // [64]
    const float* __restrict__ ln_b,     // [64]
    float* __restrict__ etab)           // [64][64]
{
  __shared__ float h[64];
  __shared__ float A1[128];
  __shared__ float xs[64];
  const int r = blockIdx.x;
  const int t = threadIdx.x;

  if (t < 64) h[t] = embed[r * 64 + t];
  __syncthreads();

  {
    float acc = ff_b1[t];
    #pragma unroll 8
    for (int k = 0; k < 64; ++k)
      acc = fmaf(h[k], ff_w1[k * 128 + t], acc);
    A1[t] = fmaxf(acc, 0.f);
  }
  __syncthreads();

  if (t < 64) {
    float acc = ff_b2[t];
    #pragma unroll 8
    for (int k = 0; k < 128; ++k)
      acc = fmaf(A1[k], ff_w2[k * 64 + t], acc);
    xs[t] = acc + h[t];
  }
  __syncthreads();

  if (t < 64) {
    float s1 = 0.f;
    if (t < 4)
      for (int j = 0; j < 16; ++j) s1 += xs[t + 4 * j];
    s1 += __shfl_xor(s1, 1);
    s1 += __shfl_xor(s1, 2);
    s1 = __shfl(s1, 0);
    float mu = s1 * 0.015625f;

    float s2 = 0.f;
    if (t < 4)
      for (int j = 0; j < 16; ++j) {
        float d = xs[t + 4 * j] - mu;
        s2 = fmaf(d, d, s2);
      }
    s2 += __shfl_xor(s2, 1);
    s2 += __shfl_xor(s2, 2);
    s2 = __shfl(s2, 0);
    float var = s2 * 0.015625f;
    float rs  = rsqrtf(var + 1e-5f);

    etab[r * 64 + t] = fmaf((xs[t] - mu) * rs, ln_g[t], ln_b[t]);
  }
}

// ---------- Kernel 2: 2-wave-per-sample 8-step Adam (r9 body, bit-exact) ----------
__device__ __forceinline__ void adam_upd(float& p, float& m, float& v,
                                         float g1, float g2, float cmsbr) {
  m = fmaf(0.9f, m, g1);
  v = fmaf(0.999f, v, g2);
  p = fmaf(-(m * cmsbr), __builtin_amdgcn_rsqf(fmaxf(v, 1e-30f)), p);
}

// (128,1): min-waves=1 -> 512-VGPR budget. The ~100 live floats (72 Adam
// state + temps) can live entirely in arch VGPRs; actual use ~150 still
// allows 3 waves/SIMD, so occupancy is unchanged vs the 64-VGPR+AGPR split
// the compiler's default heuristic picks — but any v_accvgpr_read/write
// traffic on the m/v state disappears. Single-variable A/B vs r9's 143 us.
__global__ __launch_bounds__(128, 1) void adapt_kernel(
    const int* __restrict__ seqs,       // [BATCH][32]
    const float* __restrict__ etab,     // [64][64]
    const float* __restrict__ mlp_w1,   // [64][24]
    const float* __restrict__ mlp_b1,   // [24]
    const float* __restrict__ mlp_w2,   // [24][64]
    const float* __restrict__ mlp_b2,   // [64]
    const float* __restrict__ out_w,    // [64][64]
    const float* __restrict__ out_b,    // [64]
    float* __restrict__ out)            // [BATCH][64]
{
  __shared__ float ybuf[2][2][64];     // [step parity][wave][col]
  __shared__ float hqv[64];
  const int t    = threadIdx.x;        // 0..127
  const int lane = t & 63;
  const int w    = t >> 6;             // 0 or 1
  const int s    = blockIdx.x;
  const int i0   = 12 * w;

  int tok = (lane < NPOS) ? seqs[s * SEQN + 14 + lane] : 0;

  // state: lane j owns w1[j][i0..i0+12), w2[i0..i0+12)[j];
  // lanes<12 own b1[i0+lane]; wave0 owns b2[lane].
  float w1r[12], m1[12], v1[12], w2c[12], m2[12], v2[12];
  #pragma unroll
  for (int i = 0; i < 12; ++i) {
    w1r[i] = mlp_w1[lane * 24 + i0 + i];
    w2c[i] = mlp_w2[(i0 + i) * 64 + lane];
    m1[i] = 0.f; v1[i] = 0.f; m2[i] = 0.f; v2[i] = 0.f;
  }
  float b1o = (lane < 12) ? mlp_b1[i0 + lane] : 0.f;
  float b2o = (w == 0) ? mlp_b2[lane] : 0.f;
  float mb1 = 0.f, vb1 = 0.f, mb2 = 0.f, vb2 = 0.f;

  // first k,v rows (direct from L2-resident etab)
  int tk = __shfl(tok, 0), tv = __shfl(tok, 1);
  float kj = etab[tk * 64 + lane];
  float vj = etab[tv * 64 + lane];

  #pragma unroll 1
  for (int st = 0; st < 8; ++st) {
    const float cmsbr = CMSBR[st];

    // forward: z_i (i in wave's half) = allred(k_j * w1[j][i]) + b1
    float zp[12];
    #pragma unroll
    for (int i = 0; i < 12; ++i) zp[i] = kj * w1r[i];
    #pragma unroll
    for (int i = 0; i < 12; ++i) zp[i] += (lane == i) ? b1o : 0.f;
    #pragma unroll
    for (int i = 0; i < 12; ++i) zp[i] = allred64(zp[i]);

    float a[12];
    #pragma unroll
    for (int i = 0; i < 12; ++i) a[i] = fmaxf(zp[i], 0.f);

    // y partial over this wave's 12 inner dims; b2 only in wave0's partial
    float yp = (w == 0) ? b2o : 0.f;
    #pragma unroll
    for (int i = 0; i < 12; ++i) yp = fmaf(a[i], w2c[i], yp);
    ybuf[st & 1][w][lane] = yp;
    __syncthreads();
    float y = ybuf[st & 1][0][lane] + ybuf[st & 1][1][lane];
    float dy = (y - vj) * 0.03125f;   // 2/64

    // prefetch next step's k,v (st=7 harmlessly loads q row twice)
    int p1 = 2 * st + 2; p1 = p1 < 16 ? p1 : 16;
    int p2 = 2 * st + 3; p2 = p2 < 16 ? p2 : 16;
    int tk2 = __shfl(tok, p1), tv2 = __shfl(tok, p2);
    float kn = etab[tk2 * 64 + lane];
    float vn = etab[tv2 * 64 + lane];

    // backward: dz_i = (z_i>0) * allred(w2[i][c]*dy_c)
    float dz[12];
    #pragma unroll
    for (int i = 0; i < 12; ++i) dz[i] = w2c[i] * dy;
    #pragma unroll
    for (int i = 0; i < 12; ++i) dz[i] = allred64(dz[i]);
    #pragma unroll
    for (int i = 0; i < 12; ++i) dz[i] = (a[i] > 0.f) ? dz[i] : 0.f;

    // Adam step st+1; gradient prefactors folded per step
    float kj01 = 0.1f   * kj;
    float kjsq = 0.001f * kj * kj;
    float dy01 = 0.1f   * dy;
    float dysq = 0.001f * dy * dy;
    #pragma unroll
    for (int i = 0; i < 12; ++i)
      adam_upd(w1r[i], m1[i], v1[i], kj01 * dz[i], kjsq * (dz[i] * dz[i]), cmsbr);
    #pragma unroll
    for (int i = 0; i < 12; ++i)
      adam_upd(w2c[i], m2[i], v2[i], dy01 * a[i], dysq * (a[i] * a[i]), cmsbr);
    adam_upd(b2o, mb2, vb2, dy01, dysq, cmsbr);      // wave1's copy never read
    float gb1 = 0.f;
    #pragma unroll
    for (int i = 0; i < 12; ++i) gb1 = (lane == i) ? dz[i] : gb1;
    adam_upd(b1o, mb1, vb1, 0.1f * gb1, 0.001f * (gb1 * gb1), cmsbr);

    kj = kn; vj = vn;
  }

  // final forward with q (kj holds q row after last prefetch)
  float zq[12];
  #pragma unroll
  for (int i = 0; i < 12; ++i) zq[i] = kj * w1r[i];
  #pragma unroll
  for (int i = 0; i < 12; ++i) zq[i] += (lane == i) ? b1o : 0.f;
  #pragma unroll
  for (int i = 0; i < 12; ++i) zq[i] = allred64(zq[i]);
  float hp = (w == 0) ? b2o : 0.f;
  #pragma unroll
  for (int i = 0; i < 12; ++i) hp = fmaf(fmaxf(zq[i], 0.f), w2c[i], hp);

  ybuf[0][w][lane] = hp;
  __syncthreads();
  hqv[lane] = ybuf[0][0][lane] + ybuf[0][1][lane];  // both waves, same bits
  __syncthreads();

  if (w == 0) {
    // out[s][c] = sum_j hq[j] * out_w[j][c] + out_b[c]   (lane = c)
    float acc = out_b[lane];
    const f32x4* hv = (const f32x4*)hqv;
    #pragma unroll
    for (int j4 = 0; j4 < 16; ++j4) {
      f32x4 h4 = hv[j4];
      acc = fmaf(h4.x, out_w[(4 * j4 + 0) * 64 + lane], acc);
      acc = fmaf(h4.y, out_w[(4 * j4 + 1) * 64 + lane], acc);
      acc = fmaf(h4.z, out_w[(4 * j4 + 2) * 64 + lane], acc);
      acc = fmaf(h4.w, out_w[(4 * j4 + 3) * 64 + lane], acc);
    }
    out[(size_t)s * 64 + lane] = acc;
  }
}

extern "C" void kernel_launch(void* const* d_in, const int* in_sizes, int n_in,
                              void* d_out, int out_size, void* d_ws, size_t ws_size,
                              hipStream_t stream) {
  const int*   seqs   = (const int*)d_in[0];
  const float* embed  = (const float*)d_in[1];
  const float* ff_w1  = (const float*)d_in[2];
  const float* ff_b1  = (const float*)d_in[3];
  const float* ff_w2  = (const float*)d_in[4];
  const float* ff_b2  = (const float*)d_in[5];
  const float* ln_g   = (const float*)d_in[6];
  const float* ln_b   = (const float*)d_in[7];
  const float* mlp_w1 = (const float*)d_in[8];
  const float* mlp_b1 = (const float*)d_in[9];
  const float* mlp_w2 = (const float*)d_in[10];
  const float* mlp_b2 = (const float*)d_in[11];
  const float* out_w  = (const float*)d_in[12];
  const float* out_b  = (const float*)d_in[13];

  float* etab = (float*)d_ws;   // 64*64 f32 = 16 KB

  build_table<<<64, 128, 0, stream>>>(
      embed, ff_w1, ff_b1, ff_w2, ff_b2, ln_g, ln_b, etab);
  adapt_kernel<<<BATCHN, 128, 0, stream>>>(
      seqs, etab, mlp_w1, mlp_b1, mlp_w2, mlp_b2, out_w, out_b,
      (float*)d_out);
}

// Round 12
// 206.283 us; speedup vs baseline: 1.0167x; 1.0149x over previous
//
#include <hip/hip_runtime.h>
#include <hip/hip_bf16.h>
#include <math.h>

// Problem constants
#define HID   64
#define VOCABN 64
#define INNER 24
#define SEQN  32
#define CAPN  8
#define NPOS  17
#define BATCHN 8192

typedef float f32x4 __attribute__((ext_vector_type(4)));

// Per-step Adam prefactor (double-precision offline):
//   cmsbr[t] = LR * sqrt(1 - B2^(t+1)) / (1 - B1^(t+1)),  t = 0..7
static __device__ const float CMSBR[8] = {
  0.01581139f, 0.01176584f, 0.01010053f, 0.00918844f,
  0.00862495f, 0.00825540f, 0.00800653f, 0.00783856f
};

// ---------- cross-lane all-reduce, xor-butterfly (bit-exact lineage r4-r11) ----------
__device__ __forceinline__ float allred64(float x) {
  int y;
  y = __builtin_amdgcn_update_dpp(__float_as_int(x), __float_as_int(x),
                                  0xB1, 0xF, 0xF, false);   // quad_perm xor1
  x += __int_as_float(y);
  y = __builtin_amdgcn_update_dpp(__float_as_int(x), __float_as_int(x),
                                  0x4E, 0xF, 0xF, false);   // quad_perm xor2
  x += __int_as_float(y);
  x += __int_as_float(__builtin_amdgcn_ds_swizzle(__float_as_int(x), 0x101F)); // xor4
  x += __int_as_float(__builtin_amdgcn_ds_swizzle(__float_as_int(x), 0x201F)); // xor8
  x += __int_as_float(__builtin_amdgcn_ds_swizzle(__float_as_int(x), 0x401F)); // xor16
  x += __shfl_xor(x, 32);
  return x;
}

// ---------- Kernel 1: per-token encoder table (verbatim round 6, passing) ----------
__global__ __launch_bounds__(128) void build_table(
    const float* __restrict__ embed,    // [64][64]
    const float* __restrict__ ff_w1,    // [64][128]
    const float* __restrict__ ff_b1,    // [128]
    const float* __restrict__ ff_w2,    // [128][64]
    const float* __restrict__ ff_b2,    // [64]
    const float* __restrict__ ln_g,     // [64]
    const float* __restrict__ ln_b,     // [64]
    float* __restrict__ etab)           // [64][64]
{
  __shared__ float h[64];
  __shared__ float A1[128];
  __shared__ float xs[64];
  const int r = blockIdx.x;
  const int t = threadIdx.x;

  if (t < 64) h[t] = embed[r * 64 + t];
  __syncthreads();

  {
    float acc = ff_b1[t];
    #pragma unroll 8
    for (int k = 0; k < 64; ++k)
      acc = fmaf(h[k], ff_w1[k * 128 + t], acc);
    A1[t] = fmaxf(acc, 0.f);
  }
  __syncthreads();

  if (t < 64) {
    float acc = ff_b2[t];
    #pragma unroll 8
    for (int k = 0; k < 128; ++k)
      acc = fmaf(A1[k], ff_w2[k * 64 + t], acc);
    xs[t] = acc + h[t];
  }
  __syncthreads();

  if (t < 64) {
    float s1 = 0.f;
    if (t < 4)
      for (int j = 0; j < 16; ++j) s1 += xs[t + 4 * j];
    s1 += __shfl_xor(s1, 1);
    s1 += __shfl_xor(s1, 2);
    s1 = __shfl(s1, 0);
    float mu = s1 * 0.015625f;

    float s2 = 0.f;
    if (t < 4)
      for (int j = 0; j < 16; ++j) {
        float d = xs[t + 4 * j] - mu;
        s2 = fmaf(d, d, s2);
      }
    s2 += __shfl_xor(s2, 1);
    s2 += __shfl_xor(s2, 2);
    s2 = __shfl(s2, 0);
    float var = s2 * 0.015625f;
    float rs  = rsqrtf(var + 1e-5f);

    etab[r * 64 + t] = fmaf((xs[t] - mu) * rs, ln_g[t], ln_b[t]);
  }
}

// ---------- Kernel 2: 2-wave-per-sample 8-step Adam (r9 exact, best-known) ----------
__device__ __forceinline__ void adam_upd(float& p, float& m, float& v,
                                         float g1, float g2, float cmsbr) {
  m = fmaf(0.9f, m, g1);
  v = fmaf(0.999f, v, g2);
  p = fmaf(-(m * cmsbr), __builtin_amdgcn_rsqf(fmaxf(v, 1e-30f)), p);
}

// (128,3): empirical best (r9: 143 us). A/B'd against no-hint (r10) and
// (128,1) (r11) — both ~148 us with identical VGPR_Count=64; the allocator
// pins the 64-VGPR tier regardless, and CDNA4 VALU sources the unified-file
// ACC half without measurable tax.
__global__ __launch_bounds__(128, 3) void adapt_kernel(
    const int* __restrict__ seqs,       // [BATCH][32]
    const float* __restrict__ etab,     // [64][64]
    const float* __restrict__ mlp_w1,   // [64][24]
    const float* __restrict__ mlp_b1,   // [24]
    const float* __restrict__ mlp_w2,   // [24][64]
    const float* __restrict__ mlp_b2,   // [64]
    const float* __restrict__ out_w,    // [64][64]
    const float* __restrict__ out_b,    // [64]
    float* __restrict__ out)            // [BATCH][64]
{
  __shared__ float ybuf[2][2][64];     // [step parity][wave][col]
  __shared__ float hqv[64];
  const int t    = threadIdx.x;        // 0..127
  const int lane = t & 63;
  const int w    = t >> 6;             // 0 or 1
  const int s    = blockIdx.x;
  const int i0   = 12 * w;

  int tok = (lane < NPOS) ? seqs[s * SEQN + 14 + lane] : 0;

  // state: lane j owns w1[j][i0..i0+12), w2[i0..i0+12)[j];
  // lanes<12 own b1[i0+lane]; wave0 owns b2[lane].
  float w1r[12], m1[12], v1[12], w2c[12], m2[12], v2[12];
  #pragma unroll
  for (int i = 0; i < 12; ++i) {
    w1r[i] = mlp_w1[lane * 24 + i0 + i];
    w2c[i] = mlp_w2[(i0 + i) * 64 + lane];
    m1[i] = 0.f; v1[i] = 0.f; m2[i] = 0.f; v2[i] = 0.f;
  }
  float b1o = (lane < 12) ? mlp_b1[i0 + lane] : 0.f;
  float b2o = (w == 0) ? mlp_b2[lane] : 0.f;
  float mb1 = 0.f, vb1 = 0.f, mb2 = 0.f, vb2 = 0.f;

  // first k,v rows (direct from L2-resident etab)
  int tk = __shfl(tok, 0), tv = __shfl(tok, 1);
  float kj = etab[tk * 64 + lane];
  float vj = etab[tv * 64 + lane];

  #pragma unroll 1
  for (int st = 0; st < 8; ++st) {
    const float cmsbr = CMSBR[st];

    // forward: z_i (i in wave's half) = allred(k_j * w1[j][i]) + b1
    float zp[12];
    #pragma unroll
    for (int i = 0; i < 12; ++i) zp[i] = kj * w1r[i];
    #pragma unroll
    for (int i = 0; i < 12; ++i) zp[i] += (lane == i) ? b1o : 0.f;
    #pragma unroll
    for (int i = 0; i < 12; ++i) zp[i] = allred64(zp[i]);

    float a[12];
    #pragma unroll
    for (int i = 0; i < 12; ++i) a[i] = fmaxf(zp[i], 0.f);

    // y partial over this wave's 12 inner dims; b2 only in wave0's partial
    float yp = (w == 0) ? b2o : 0.f;
    #pragma unroll
    for (int i = 0; i < 12; ++i) yp = fmaf(a[i], w2c[i], yp);
    ybuf[st & 1][w][lane] = yp;
    __syncthreads();
    float y = ybuf[st & 1][0][lane] + ybuf[st & 1][1][lane];
    float dy = (y - vj) * 0.03125f;   // 2/64

    // prefetch next step's k,v (st=7 harmlessly loads q row twice)
    int p1 = 2 * st + 2; p1 = p1 < 16 ? p1 : 16;
    int p2 = 2 * st + 3; p2 = p2 < 16 ? p2 : 16;
    int tk2 = __shfl(tok, p1), tv2 = __shfl(tok, p2);
    float kn = etab[tk2 * 64 + lane];
    float vn = etab[tv2 * 64 + lane];

    // backward: dz_i = (z_i>0) * allred(w2[i][c]*dy_c)
    float dz[12];
    #pragma unroll
    for (int i = 0; i < 12; ++i) dz[i] = w2c[i] * dy;
    #pragma unroll
    for (int i = 0; i < 12; ++i) dz[i] = allred64(dz[i]);
    #pragma unroll
    for (int i = 0; i < 12; ++i) dz[i] = (a[i] > 0.f) ? dz[i] : 0.f;

    // Adam step st+1; gradient prefactors folded per step
    float kj01 = 0.1f   * kj;
    float kjsq = 0.001f * kj * kj;
    float dy01 = 0.1f   * dy;
    float dysq = 0.001f * dy * dy;
    #pragma unroll
    for (int i = 0; i < 12; ++i)
      adam_upd(w1r[i], m1[i], v1[i], kj01 * dz[i], kjsq * (dz[i] * dz[i]), cmsbr);
    #pragma unroll
    for (int i = 0; i < 12; ++i)
      adam_upd(w2c[i], m2[i], v2[i], dy01 * a[i], dysq * (a[i] * a[i]), cmsbr);
    adam_upd(b2o, mb2, vb2, dy01, dysq, cmsbr);      // wave1's copy never read
    float gb1 = 0.f;
    #pragma unroll
    for (int i = 0; i < 12; ++i) gb1 = (lane == i) ? dz[i] : gb1;
    adam_upd(b1o, mb1, vb1, 0.1f * gb1, 0.001f * (gb1 * gb1), cmsbr);

    kj = kn; vj = vn;
  }

  // final forward with q (kj holds q row after last prefetch)
  float zq[12];
  #pragma unroll
  for (int i = 0; i < 12; ++i) zq[i] = kj * w1r[i];
  #pragma unroll
  for (int i = 0; i < 12; ++i) zq[i] += (lane == i) ? b1o : 0.f;
  #pragma unroll
  for (int i = 0; i < 12; ++i) zq[i] = allred64(zq[i]);
  float hp = (w == 0) ? b2o : 0.f;
  #pragma unroll
  for (int i = 0; i < 12; ++i) hp = fmaf(fmaxf(zq[i], 0.f), w2c[i], hp);

  ybuf[0][w][lane] = hp;
  __syncthreads();
  hqv[lane] = ybuf[0][0][lane] + ybuf[0][1][lane];  // both waves, same bits
  __syncthreads();

  if (w == 0) {
    // out[s][c] = sum_j hq[j] * out_w[j][c] + out_b[c]   (lane = c)
    float acc = out_b[lane];
    const f32x4* hv = (const f32x4*)hqv;
    #pragma unroll
    for (int j4 = 0; j4 < 16; ++j4) {
      f32x4 h4 = hv[j4];
      acc = fmaf(h4.x, out_w[(4 * j4 + 0) * 64 + lane], acc);
      acc = fmaf(h4.y, out_w[(4 * j4 + 1) * 64 + lane], acc);
      acc = fmaf(h4.z, out_w[(4 * j4 + 2) * 64 + lane], acc);
      acc = fmaf(h4.w, out_w[(4 * j4 + 3) * 64 + lane], acc);
    }
    out[(size_t)s * 64 + lane] = acc;
  }
}

extern "C" void kernel_launch(void* const* d_in, const int* in_sizes, int n_in,
                              void* d_out, int out_size, void* d_ws, size_t ws_size,
                              hipStream_t stream) {
  const int*   seqs   = (const int*)d_in[0];
  const float* embed  = (const float*)d_in[1];
  const float* ff_w1  = (const float*)d_in[2];
  const float* ff_b1  = (const float*)d_in[3];
  const float* ff_w2  = (const float*)d_in[4];
  const float* ff_b2  = (const float*)d_in[5];
  const float* ln_g   = (const float*)d_in[6];
  const float* ln_b   = (const float*)d_in[7];
  const float* mlp_w1 = (const float*)d_in[8];
  const float* mlp_b1 = (const float*)d_in[9];
  const float* mlp_w2 = (const float*)d_in[10];
  const float* mlp_b2 = (const float*)d_in[11];
  const float* out_w  = (const float*)d_in[12];
  const float* out_b  = (const float*)d_in[13];

  float* etab = (float*)d_ws;   // 64*64 f32 = 16 KB

  build_table<<<64, 128, 0, stream>>>(
      embed, ff_w1, ff_b1, ff_w2, ff_b2, ln_g, ln_b, etab);
  adapt_kernel<<<BATCHN, 128, 0, stream>>>(
      seqs, etab, mlp_w1, mlp_b1, mlp_w2, mlp_b2, out_w, out_b,
      (float*)d_out);
}